// Round 1
// baseline (108.178 us; speedup 1.0000x reference)
//
#include <hip/hip_runtime.h>
#include <math.h>

#define DEVI __device__ __forceinline__

typedef __bf16 bf16_t;
typedef bf16_t bf16x8 __attribute__((ext_vector_type(8)));
typedef float  f32x4  __attribute__((ext_vector_type(4)));

constexpr int NB   = 4;
constexpr int SEQL = 2048;
constexpr int NH   = 12;
constexpr int DHD  = 64;
constexpr int DMOD = 768;
constexpr int NT   = NB * SEQL;        // 8192 tokens
constexpr int KD   = DMOD;             // GEMM K = 768

// ---------- helpers ----------

DEVI unsigned short f2bf(float f) {    // RNE via bit-ops (prep kernels)
  union { float f; unsigned u; } v; v.f = f;
  unsigned r = v.u + 0x7FFFu + ((v.u >> 16) & 1u);
  return (unsigned short)(r >> 16);
}

DEVI unsigned short cvt_bf16(float f) { // native cvt (hot paths)
  bf16_t b = (bf16_t)f;
  return __builtin_bit_cast(unsigned short, b);
}

DEVI float exp2_raw(float x) {          // single v_exp_f32, no ocml guards
  float r;
  asm("v_exp_f32 %0, %1" : "=v"(r) : "v"(x));
  return r;
}

// async global->LDS, 16B per lane. LDS dest wave-uniform base + lane*16.
DEVI void gload16(const unsigned short* src, unsigned short* dst) {
  auto g = (const __attribute__((address_space(1))) unsigned int*)(unsigned long long)src;
  auto l = (__attribute__((address_space(3))) unsigned int*)(unsigned int)(unsigned long long)(dst);
  __builtin_amdgcn_global_load_lds(g, l, 16, 0, 0);
}

// ---------- fused prep: convert_x + prep_wqkv + prep_wo in one dispatch ----------
__global__ void __launch_bounds__(256) prep_all(const float* __restrict__ x,
                                                const float* __restrict__ WQ,
                                                const float* __restrict__ WK,
                                                const float* __restrict__ WV,
                                                const float* __restrict__ WO,
                                                unsigned short* __restrict__ xb,
                                                unsigned short* __restrict__ Wt,
                                                unsigned short* __restrict__ Wo_t) {
  __shared__ float T[64][68];
  const int bid = blockIdx.x;
  const int t = threadIdx.x;
  if (bid < 3072) {
    size_t i = ((size_t)bid * 256 + t) * 8;
    float4 a = *(const float4*)(x + i);
    float4 b = *(const float4*)(x + i + 4);
    union { unsigned short u[8]; uint4 v; } pk;
    pk.u[0] = f2bf(a.x); pk.u[1] = f2bf(a.y); pk.u[2] = f2bf(a.z); pk.u[3] = f2bf(a.w);
    pk.u[4] = f2bf(b.x); pk.u[5] = f2bf(b.y); pk.u[6] = f2bf(b.z); pk.u[7] = f2bf(b.w);
    *(uint4*)(xb + i) = pk.v;
    return;
  }
  const int r0 = t >> 4, c4 = (t & 15) * 4;
  if (bid < 3504) {
    const int u = bid - 3072;                  // 432 blocks
    const int mt = u % 12, hw = u / 12;
    const int which = hw / 12, h = hw % 12;
    const float* W = (which == 0) ? WQ : ((which == 1) ? WK : WV);
    const float* src = W + ((size_t)h * 768 + mt * 64) * 64;   // [64 m][64 d]
#pragma unroll
    for (int rep = 0; rep < 4; ++rep) {
      int m = rep * 16 + r0;
      float4 v = *(const float4*)(src + m * 64 + c4);
      T[m][c4] = v.x; T[m][c4 + 1] = v.y; T[m][c4 + 2] = v.z; T[m][c4 + 3] = v.w;
    }
    __syncthreads();
    unsigned short* dst = Wt + ((size_t)which * 768 + h * 64) * 768 + mt * 64;
#pragma unroll
    for (int rep = 0; rep < 4; ++rep) {
      int d = rep * 16 + r0;
      union { unsigned short u[4]; uint2 v; } o;
#pragma unroll
      for (int j = 0; j < 4; ++j) o.u[j] = f2bf(T[c4 + j][d]);
      *(uint2*)(dst + (size_t)d * 768 + c4) = o.v;
    }
  } else {
    const int u = bid - 3504;                  // 144 blocks
    const int m0 = (u % 12) * 64, hd0 = (u / 12) * 64;
#pragma unroll
    for (int rep = 0; rep < 4; ++rep) {
      int i = rep * 16 + r0;                   // hd-local row
      float4 v = *(const float4*)(WO + (size_t)(hd0 + i) * 768 + m0 + c4);
      T[i][c4] = v.x; T[i][c4 + 1] = v.y; T[i][c4 + 2] = v.z; T[i][c4 + 3] = v.w;
    }
    __syncthreads();
#pragma unroll
    for (int rep = 0; rep < 4; ++rep) {
      int m = rep * 16 + r0;                   // m-local row
      union { unsigned short u[4]; uint2 v; } o;
#pragma unroll
      for (int j = 0; j < 4; ++j) o.u[j] = f2bf(T[c4 + j][m]);
      *(uint2*)(Wo_t + (size_t)(m0 + m) * 768 + hd0 + c4) = o.v;
    }
  }
}

// ---------- QKV GEMM: C[M][2304] = A[M][768] * Bt[2304][768]^T ----------
// [round-12 config: 128x128, BK=64, 128B LDS rows + ^(row&7) swizzle,
// A dbuf + B single (48KB, 3 blocks/CU), packed 8B V-transpose stores,
// counted-vmcnt pipeline. 828 TF ~ 92% of the 2-barrier structure ceiling.]
__global__ void __launch_bounds__(256)
gemm_qkv(const unsigned short* __restrict__ A,
         const unsigned short* __restrict__ Bt,
         const float* __restrict__ bq, const float* __restrict__ bk,
         const float* __restrict__ bv,
         unsigned short* __restrict__ qo, unsigned short* __restrict__ ko,
         unsigned short* __restrict__ vo) {
  __shared__ __align__(16) unsigned short ldsA[2 * 8192];   // [buf][128 r][64 k]
  __shared__ __align__(16) unsigned short ldsB[8192];       // [128 r][64 k] single
  const int bm = blockIdx.x, bn = blockIdx.y;
  const int m0 = bm * 128, n0 = bn * 128;
  const int tid = threadIdx.x, w = tid >> 6, lane = tid & 63;
  const int g = lane >> 4, r16 = lane & 15;
  const int wm = w >> 1, wn = w & 1;

  const int ss = (lane & 7) ^ ((lane >> 3) & 7);
  const unsigned short* asrc = A  + (size_t)(m0 + (lane >> 3)) * KD + ss * 8;
  const unsigned short* bsrc = Bt + (size_t)(n0 + (lane >> 3)) * KD + ss * 8;

  auto stageA = [&](int buf, int kt) {     // 4 gloads per wave
#pragma unroll
    for (int j = 0; j < 4; ++j) {
      int seg = w * 4 + j;
      gload16(asrc + (size_t)(seg * 8) * KD + kt * 64, ldsA + buf * 8192 + seg * 512);
    }
  };
  auto stageB = [&](int kt) {              // 4 gloads per wave
#pragma unroll
    for (int j = 0; j < 4; ++j) {
      int seg = w * 4 + j;
      gload16(bsrc + (size_t)(seg * 8) * KD + kt * 64, ldsB + seg * 512);
    }
  };

  const int r7 = r16 & 7;
  const int aoff0 = r16 * 64 + ((g    ) ^ r7) * 8;   // k-chunk g   (kk=0)
  const int aoff1 = r16 * 64 + ((g + 4) ^ r7) * 8;   // k-chunk g+4 (kk=1)

  f32x4 acc[4][4];
  const f32x4 zero4 = {0.f, 0.f, 0.f, 0.f};
#pragma unroll
  for (int i = 0; i < 4; ++i)
#pragma unroll
    for (int j = 0; j < 4; ++j) acc[i][j] = zero4;

  constexpr int NKT = KD / 64;   // 12
  stageA(0, 0);
  stageB(0);
  int buf = 0;
  for (int kt = 0; kt < NKT; ++kt) {
    if (kt + 1 < NKT) {
      stageA(buf ^ 1, kt + 1);
      asm volatile("s_waitcnt vmcnt(4)" ::: "memory");   // A(t)+B(t) landed
    } else {
      asm volatile("s_waitcnt vmcnt(0)" ::: "memory");
    }
    __builtin_amdgcn_s_barrier();                        // everyone's landed
    const unsigned short* Ab = ldsA + buf * 8192 + wm * 4096;
    const unsigned short* Bb = ldsB + wn * 4096;
    bf16x8 af[2][4], bfr[2][4];
#pragma unroll
    for (int f = 0; f < 4; ++f) {
      af[0][f]  = *(const bf16x8*)&Ab[aoff0 + f * 1024];
      af[1][f]  = *(const bf16x8*)&Ab[aoff1 + f * 1024];
      bfr[0][f] = *(const bf16x8*)&Bb[aoff0 + f * 1024];
      bfr[1][f] = *(const bf16x8*)&Bb[aoff1 + f * 1024];
    }
#pragma unroll
    for (int kk = 0; kk < 2; ++kk)
#pragma unroll
      for (int fm = 0; fm < 4; ++fm)
#pragma unroll
        for (int fn = 0; fn < 4; ++fn)
          acc[fm][fn] = __builtin_amdgcn_mfma_f32_16x16x32_bf16(af[kk][fm], bfr[kk][fn],
                                                                acc[fm][fn], 0, 0, 0);
    asm volatile("s_waitcnt lgkmcnt(0)" ::: "memory");   // all ds_reads returned
    __builtin_amdgcn_s_barrier();                        // B buffer now dead
    if (kt + 1 < NKT) stageB(kt + 1);                    // refill B immediately
    buf ^= 1;
  }

#pragma unroll
  for (int fm = 0; fm < 4; ++fm) {
#pragma unroll
    for (int fn = 0; fn < 4; ++fn) {
      const int col = n0 + wn * 64 + fn * 16 + r16;
      const int rbase = m0 + wm * 64 + fm * 16 + g * 4;
      const int which = (col >= 1536) ? 2 : ((col >= 768) ? 1 : 0);
      const int hd = col - which * 768;
      const int h = hd >> 6, d = hd & 63;
      const float bias = (which == 0 ? bq : which == 1 ? bk : bv)[hd];
      if (which == 2) {
        // V transposed: vt[bh][d][s]; 4 r-values are s-consecutive -> 8B store
        union { unsigned short u[4]; uint2 v; } o;
#pragma unroll
        for (int r = 0; r < 4; ++r) o.u[r] = cvt_bf16(acc[fm][fn][r] + bias);
        const int b = rbase >> 11, s = rbase & (SEQL - 1);
        *(uint2*)(vo + ((size_t)(b * NH + h) * DHD + d) * SEQL + s) = o.v;
      } else {
#pragma unroll
        for (int r = 0; r < 4; ++r) {
          int row = rbase + r;
          int b = row >> 11, s = row & (SEQL - 1);
          float v = acc[fm][fn][r] + bias;
          if (which == 0)  // fold 1/sqrt(64)*log2(e) so attn uses exp2 directly
            qo[((size_t)(b * NH + h) * SEQL + s) * DHD + d] = cvt_bf16(v * 0.1803368801111f);
          else
            ko[((size_t)(b * NH + h) * SEQL + s) * DHD + d] = cvt_bf16(v);
        }
      }
    }
  }
}

// ---------- O-proj GEMM: out[M][768] = z[M][768] * Wo_t[768][768]^T + bO ----------
// [round-15 config: 64x128 tile, grid (128,6)=768 blocks=3/CU on all CUs.]
__global__ void __launch_bounds__(256)
gemm_o(const unsigned short* __restrict__ A,
       const unsigned short* __restrict__ Bt,
       const float* __restrict__ bo, float* __restrict__ fout) {
  __shared__ __align__(16) unsigned short ldsA[2 * 4096];   // [buf][64 r][64 k]
  __shared__ __align__(16) unsigned short ldsB[8192];       // [128 r][64 k] single
  const int bm = blockIdx.x, bn = blockIdx.y;
  const int m0 = bm * 64, n0 = bn * 128;
  const int tid = threadIdx.x, w = tid >> 6, lane = tid & 63;
  const int g = lane >> 4, r16 = lane & 15;
  const int wm = w >> 1, wn = w & 1;

  const int ss = (lane & 7) ^ ((lane >> 3) & 7);
  const unsigned short* asrc = A  + (size_t)(m0 + (lane >> 3)) * KD + ss * 8;
  const unsigned short* bsrc = Bt + (size_t)(n0 + (lane >> 3)) * KD + ss * 8;

  auto stageA = [&](int buf, int kt) {     // 2 gloads per wave
#pragma unroll
    for (int j = 0; j < 2; ++j) {
      int seg = w * 2 + j;
      gload16(asrc + (size_t)(seg * 8) * KD + kt * 64, ldsA + buf * 4096 + seg * 512);
    }
  };
  auto stageB = [&](int kt) {              // 4 gloads per wave
#pragma unroll
    for (int j = 0; j < 4; ++j) {
      int seg = w * 4 + j;
      gload16(bsrc + (size_t)(seg * 8) * KD + kt * 64, ldsB + seg * 512);
    }
  };

  const int r7 = r16 & 7;
  const int aoff0 = r16 * 64 + ((g    ) ^ r7) * 8;
  const int aoff1 = r16 * 64 + ((g + 4) ^ r7) * 8;

  f32x4 acc[2][4];
  const f32x4 zero4 = {0.f, 0.f, 0.f, 0.f};
#pragma unroll
  for (int i = 0; i < 2; ++i)
#pragma unroll
    for (int j = 0; j < 4; ++j) acc[i][j] = zero4;

  constexpr int NKT = KD / 64;   // 12
  stageA(0, 0);
  stageB(0);
  int buf = 0;
  for (int kt = 0; kt < NKT; ++kt) {
    if (kt + 1 < NKT) {
      stageA(buf ^ 1, kt + 1);
      asm volatile("s_waitcnt vmcnt(2)" ::: "memory");
    } else {
      asm volatile("s_waitcnt vmcnt(0)" ::: "memory");
    }
    __builtin_amdgcn_s_barrier();
    const unsigned short* Ab = ldsA + buf * 4096 + wm * 2048;   // 32 rows
    const unsigned short* Bb = ldsB + wn * 4096;                // 64 rows
    bf16x8 af[2][2], bfr[2][4];
#pragma unroll
    for (int f = 0; f < 2; ++f) {
      af[0][f] = *(const bf16x8*)&Ab[aoff0 + f * 1024];
      af[1][f] = *(const bf16x8*)&Ab[aoff1 + f * 1024];
    }
#pragma unroll
    for (int f = 0; f < 4; ++f) {
      bfr[0][f] = *(const bf16x8*)&Bb[aoff0 + f * 1024];
      bfr[1][f] = *(const bf16x8*)&Bb[aoff1 + f * 1024];
    }
#pragma unroll
    for (int kk = 0; kk < 2; ++kk)
#pragma unroll
      for (int fm = 0; fm < 2; ++fm)
#pragma unroll
        for (int fn = 0; fn < 4; ++fn)
          acc[fm][fn] = __builtin_amdgcn_mfma_f32_16x16x32_bf16(af[kk][fm], bfr[kk][fn],
                                                                acc[fm][fn], 0, 0, 0);
    asm volatile("s_waitcnt lgkmcnt(0)" ::: "memory");
    __builtin_amdgcn_s_barrier();
    if (kt + 1 < NKT) stageB(kt + 1);
    buf ^= 1;
  }

#pragma unroll
  for (int fm = 0; fm < 2; ++fm) {
#pragma unroll
    for (int fn = 0; fn < 4; ++fn) {
      const int col = n0 + wn * 64 + fn * 16 + r16;
      const int rbase = m0 + wm * 32 + fm * 16 + g * 4;
      const float bias = bo[col];
#pragma unroll
      for (int r = 0; r < 4; ++r)
        fout[(size_t)(rbase + r) * DMOD + col] = acc[fm][fn][r] + bias;
    }
  }
}

// ---------- flash attention (causal, paired q-tiles, single-barrier dbuf) ----------
// Round 19: 2-stage kv software pipeline. The round-18 chain per tile was
//   barrier; stage(t+1); vmcnt; QK(t) -> softmax(t) -> P roundtrip -> PV(t)
// fully serial per wave (MfmaUtil 21%, VALUBusy 33%, both pipes mostly idle,
// latency-bound at 3 waves/SIMD). Now QK(t+1) issues at the END of iter t,
// right after PV(t), reading the double-buffered K(t+1) staged at the top of
// this iter. QK's MFMA issue+latency overlaps barrier+softmax of iter t+1.
// Single sacc register buffer: in-order issue guarantees SM(t)'s reads of
// sacc precede QK(t+1)'s writes (register WAR, free; no runtime-indexed
// arrays -> no scratch). Prologue is fully safe (stage; vmcnt(0); barrier;
// QK(0)). Steady-state cross-wave RAW on the staged tile keeps the same
// own-vmcnt + barrier-correlation argument as round 18.
// grid 768 = 16 qp x 48 bh, id = qp*48+bh (same-bh -> same XCD since 48%8==0).
__global__ void __launch_bounds__(256, 3)
attn_fwd(const unsigned short* __restrict__ qb,
         const unsigned short* __restrict__ kb,
         const unsigned short* __restrict__ vt,
         unsigned short* __restrict__ zb) {
  __shared__ __align__(16) unsigned short ldsK[2 * 4096];  // [buf][kv 64][d 64] swz
  __shared__ __align__(16) unsigned short ldsV[2 * 4096];  // [buf][d 64][kv 64] swz
  __shared__ __align__(16) unsigned short ldsP[4 * 1024];  // per-wave [q 16][kv 64] swz
  const int id = blockIdx.x;
  const int qp = id / 48, bh = id % 48;
  const int qtA = qp, qtB = 31 - qp;
  const int tid = threadIdx.x, w = tid >> 6, lane = tid & 63;
  const int g = lane >> 4, r16 = lane & 15;
  const int r7 = r16 & 7;

  // staging source bases (lane-constant)
  const int sslot = (lane & 7) ^ (lane >> 3);
  const unsigned short* ksrc = kb + (size_t)bh * SEQL * DHD + (lane >> 3) * 64 + sslot * 8;
  const unsigned short* vsrc = vt + (size_t)bh * SEQL * DHD + (lane >> 3) * 2048 + sslot * 8;

  auto stage = [&](int buf, int kv0) {     // 4 gloads per wave
#pragma unroll
    for (int j = 0; j < 2; ++j) {
      int seg = w * 2 + j;
      gload16(ksrc + kv0 * 64 + seg * 512, ldsK + buf * 4096 + seg * 512);
      gload16(vsrc + kv0 + seg * 16384,    ldsV + buf * 4096 + seg * 512);
    }
  };

  // K/V fragment offsets, ushort units (row&7 == r16&7 for all frag rows)
  const int roff0 = r16 * 64 + ((g    ) ^ r7) * 8;   // d/kv chunk kk=0
  const int roff1 = r16 * 64 + ((g + 4) ^ r7) * 8;   // kk=1
  // P buffer: row q=r16 (128B), 8 chunks of 16B, chunk swizzle c ^= r7.
  char* const pwb = (char*)ldsP + w * 2048;
  int paddr[4];
#pragma unroll
  for (int fn = 0; fn < 4; ++fn)
    paddr[fn] = r16 * 128 + ((((fn * 2) + (g >> 1)) ^ r7) << 4) + ((g & 1) << 3);
  const int prd0 = r16 * 128 + (((g    ) ^ r7) << 4);
  const int prd1 = r16 * 128 + (((g + 4) ^ r7) << 4);
  const int thr = w * 16 + r16 - g * 4;   // causal: mask if fn*16 + r > thr

  // Q fragments for both passes (B-operand: col=q=r16, k=d=g*8..)
  bf16x8 qfA[2], qfB[2];
  {
    const unsigned short* qa = qb + ((size_t)bh * SEQL + qtA * 64 + w * 16 + r16) * DHD + g * 8;
    const unsigned short* qc = qb + ((size_t)bh * SEQL + qtB * 64 + w * 16 + r16) * DHD + g * 8;
    qfA[0] = *(const bf16x8*)qa; qfA[1] = *(const bf16x8*)(qa + 32);
    qfB[0] = *(const bf16x8*)qc; qfB[1] = *(const bf16x8*)(qc + 32);
  }

  float laccA = 0.f, laccB = 0.f;
  f32x4 zaccA[4], zaccB[4], sacc[4];
  const f32x4 zero4 = {0.f, 0.f, 0.f, 0.f};
#pragma unroll
  for (int r = 0; r < 4; ++r) { zaccA[r] = zero4; zaccB[r] = zero4; }

  // QK^T for one tile into the (single) sacc register buffer.
  // Swapped operands: A = K-frag, B = Q-frag -> lane holds q = r16.
  auto qk_issue = [&](bf16x8 q0, bf16x8 q1, int nb) {
    const unsigned short* Kb = ldsK + nb * 4096;
    __builtin_amdgcn_s_setprio(1);
#pragma unroll
    for (int fn = 0; fn < 4; ++fn) {
      bf16x8 kf = *(const bf16x8*)&Kb[roff0 + fn * 1024];
      sacc[fn] = __builtin_amdgcn_mfma_f32_16x16x32_bf16(kf, q0, zero4, 0, 0, 0);
    }
#pragma unroll
    for (int fn = 0; fn < 4; ++fn) {
      bf16x8 kf = *(const bf16x8*)&Kb[roff1 + fn * 1024];
      sacc[fn] = __builtin_amdgcn_mfma_f32_16x16x32_bf16(kf, q1, sacc[fn], 0, 0, 0);
    }
    __builtin_amdgcn_s_setprio(0);
  };

  // softmax + P roundtrip + PV for the tile whose scores are in sacc.
  auto smpv = [&](float& lacc, f32x4* zacc, int buf, bool diag) {
    const unsigned short* Vb = ldsV + buf * 4096;
    if (diag) {                              // kv = fn*16+g*4+r > q = w*16+r16
#pragma unroll
      for (int fn = 0; fn < 4; ++fn)
#pragma unroll
        for (int r = 0; r < 4; ++r)
          if (fn * 16 + r > thr) sacc[fn][r] = -3.0e38f;
    }
    // p = exp2(s') via raw v_exp_f32; scalar row-sum; pack + b64 P store
#pragma unroll
    for (int fn = 0; fn < 4; ++fn) {
      float p0 = exp2_raw(sacc[fn][0]), p1 = exp2_raw(sacc[fn][1]);
      float p2 = exp2_raw(sacc[fn][2]), p3 = exp2_raw(sacc[fn][3]);
      lacc += (p0 + p1) + (p2 + p3);
      unsigned w0, w1;
      asm("v_cvt_pk_bf16_f32 %0, %1, %2" : "=v"(w0) : "v"(p0), "v"(p1));
      asm("v_cvt_pk_bf16_f32 %0, %1, %2" : "=v"(w1) : "v"(p2), "v"(p3));
      uint2 pk; pk.x = w0; pk.y = w1;
      *(uint2*)(pwb + paddr[fn]) = pk;       // ds_write_b64, addr hoisted
    }
    asm volatile("" ::: "memory");           // order P stores before P reads
    bf16x8 pf0 = *(const bf16x8*)(pwb + prd0);
    bf16x8 pf1 = *(const bf16x8*)(pwb + prd1);
    __builtin_amdgcn_s_setprio(1);
#pragma unroll
    for (int fn = 0; fn < 4; ++fn) {
      bf16x8 vf = *(const bf16x8*)&Vb[roff0 + fn * 1024];
      zacc[fn] = __builtin_amdgcn_mfma_f32_16x16x32_bf16(pf0, vf, zacc[fn], 0, 0, 0);
    }
#pragma unroll
    for (int fn = 0; fn < 4; ++fn) {
      bf16x8 vf = *(const bf16x8*)&Vb[roff1 + fn * 1024];
      zacc[fn] = __builtin_amdgcn_mfma_f32_16x16x32_bf16(pf1, vf, zacc[fn], 0, 0, 0);
    }
    __builtin_amdgcn_s_setprio(0);
  };

  // ---- prologue: fully safe (everyone's tile-0 loads landed before QK(0)) ----
  stage(0, 0);
  asm volatile("s_waitcnt vmcnt(0)" ::: "memory");
  __builtin_amdgcn_s_barrier();
  qk_issue(qfA[0], qfA[1], 0);

  int buf = 0;
  // ---- pass A: kv tiles 0..qtA ----
  for (int kt = 0; kt <= qtA; ++kt) {
    __builtin_amdgcn_s_barrier();            // all reads of buf^1 (tile t-1) retired
    int nkv = (kt < qtA) ? (kt + 1) * 64 : 0;   // seam: prefetch pass-B tile 0
    stage(buf ^ 1, nkv);
    smpv(laccA, zaccA, buf, kt == qtA);      // consumes sacc (scores of tile kt)
    asm volatile("s_waitcnt vmcnt(0)" ::: "memory");   // tile kt+1 landed (own)
    if (kt < qtA) qk_issue(qfA[0], qfA[1], buf ^ 1);
    else          qk_issue(qfB[0], qfB[1], buf ^ 1);   // seam: QK of B tile 0
    buf ^= 1;
  }
  // ---- pass B: kv tiles 0..qtB ----
  for (int kt = 0; kt <= qtB; ++kt) {
    __builtin_amdgcn_s_barrier();
    if (kt < qtB) {
      stage(buf ^ 1, (kt + 1) * 64);
      smpv(laccB, zaccB, buf, false);
      asm volatile("s_waitcnt vmcnt(0)" ::: "memory");
      qk_issue(qfB[0], qfB[1], buf ^ 1);
    } else {
      smpv(laccB, zaccB, buf, true);         // diagonal tile, no prefetch
    }
    buf ^= 1;
  }

  // epilogue: cross-group l-reduce (groups hold disjoint kv), normalize, store
  laccA += __shfl_xor(laccA, 16); laccA += __shfl_xor(laccA, 32);
  laccB += __shfl_xor(laccB, 16); laccB += __shfl_xor(laccB, 32);
  const float invA = 1.0f / laccA;   // valid for q = r16 at every lane
  const float invB = 1.0f / laccB;
  const int b = bh / NH, h = bh % NH;
#pragma unroll
  for (int r = 0; r < 4; ++r) {
    // zacc row q' = g*4+r; its inv lives at lane q' (r16=q', group 0)
    float iar = __shfl(invA, g * 4 + r);
    float ibr = __shfl(invB, g * 4 + r);
    int sA = qtA * 64 + w * 16 + g * 4 + r;
    int sB = qtB * 64 + w * 16 + g * 4 + r;
#pragma unroll
    for (int fn = 0; fn < 4; ++fn) {
      int d = fn * 16 + r16;
      zb[((size_t)(b * SEQL + sA)) * DMOD + h * DHD + d] = cvt_bf16(zaccA[fn][r] * iar);
      zb[((size_t)(b * SEQL + sB)) * DMOD + h * DHD + d] = cvt_bf16(zaccB[fn][r] * ibr);
    }
  }
}

// ---------- launch ----------

extern "C" void kernel_launch(void* const* d_in, const int* in_sizes, int n_in,
                              void* d_out, int out_size, void* d_ws, size_t ws_size,
                              hipStream_t stream) {
  const float* x  = (const float*)d_in[0];
  const float* WQ = (const float*)d_in[1];
  const float* WK = (const float*)d_in[2];
  const float* WV = (const float*)d_in[3];
  const float* WO = (const float*)d_in[4];
  const float* bQ = (const float*)d_in[5];
  const float* bK = (const float*)d_in[6];
  const float* bV = (const float*)d_in[7];
  const float* bO = (const float*)d_in[8];
  float* out = (float*)d_out;

  constexpr size_t NE = (size_t)NT * DMOD;
  unsigned short* w0   = (unsigned short*)d_ws;
  unsigned short* Wqkv = w0;                         // 3*768*768
  unsigned short* Wo   = Wqkv + (size_t)3 * 768 * 768;
  unsigned short* xb   = Wo + (size_t)768 * 768;
  unsigned short* qb   = xb + NE;
  unsigned short* kb   = qb + NE;
  unsigned short* vt   = kb + NE;                    // [bh][d][s]
  unsigned short* zb   = xb;                         // alias: xb dead after QKV GEMM
  size_t need = (size_t)(vt + NE - w0) * sizeof(unsigned short);
  if (ws_size < need) return;

  prep_all<<<3648, 256, 0, stream>>>(x, WQ, WK, WV, WO, xb, Wqkv, Wo);
  gemm_qkv<<<dim3(64, 18), 256, 0, stream>>>(xb, Wqkv, bQ, bK, bV, qb, kb, vt);
  attn_fwd<<<768, 256, 0, stream>>>(qb, kb, vt, zb);
  gemm_o<<<dim3(128, 6), 256, 0, stream>>>(zb, Wo, bO, out);
}

// Round 2
// 105.402 us; speedup vs baseline: 1.0263x; 1.0263x over previous
//
#include <hip/hip_runtime.h>
#include <math.h>

#define DEVI __device__ __forceinline__

typedef __bf16 bf16_t;
typedef bf16_t bf16x8 __attribute__((ext_vector_type(8)));
typedef float  f32x4  __attribute__((ext_vector_type(4)));

constexpr int NB   = 4;
constexpr int SEQL = 2048;
constexpr int NH   = 12;
constexpr int DHD  = 64;
constexpr int DMOD = 768;
constexpr int NT   = NB * SEQL;        // 8192 tokens
constexpr int KD   = DMOD;             // GEMM K = 768

// ---------- helpers ----------

DEVI unsigned short f2bf(float f) {    // RNE via bit-ops (prep kernels)
  union { float f; unsigned u; } v; v.f = f;
  unsigned r = v.u + 0x7FFFu + ((v.u >> 16) & 1u);
  return (unsigned short)(r >> 16);
}

DEVI unsigned short cvt_bf16(float f) { // native cvt (hot paths)
  bf16_t b = (bf16_t)f;
  return __builtin_bit_cast(unsigned short, b);
}

DEVI float exp2_raw(float x) {          // single v_exp_f32, no ocml guards
  float r;
  asm("v_exp_f32 %0, %1" : "=v"(r) : "v"(x));
  return r;
}

// async global->LDS, 16B per lane. LDS dest wave-uniform base + lane*16.
DEVI void gload16(const unsigned short* src, unsigned short* dst) {
  auto g = (const __attribute__((address_space(1))) unsigned int*)(unsigned long long)src;
  auto l = (__attribute__((address_space(3))) unsigned int*)(unsigned int)(unsigned long long)(dst);
  __builtin_amdgcn_global_load_lds(g, l, 16, 0, 0);
}

// ---------- fused prep: convert_x + prep_wqkv + prep_wo in one dispatch ----------
__global__ void __launch_bounds__(256) prep_all(const float* __restrict__ x,
                                                const float* __restrict__ WQ,
                                                const float* __restrict__ WK,
                                                const float* __restrict__ WV,
                                                const float* __restrict__ WO,
                                                unsigned short* __restrict__ xb,
                                                unsigned short* __restrict__ Wt,
                                                unsigned short* __restrict__ Wo_t) {
  __shared__ float T[64][68];
  const int bid = blockIdx.x;
  const int t = threadIdx.x;
  if (bid < 3072) {
    size_t i = ((size_t)bid * 256 + t) * 8;
    float4 a = *(const float4*)(x + i);
    float4 b = *(const float4*)(x + i + 4);
    union { unsigned short u[8]; uint4 v; } pk;
    pk.u[0] = f2bf(a.x); pk.u[1] = f2bf(a.y); pk.u[2] = f2bf(a.z); pk.u[3] = f2bf(a.w);
    pk.u[4] = f2bf(b.x); pk.u[5] = f2bf(b.y); pk.u[6] = f2bf(b.z); pk.u[7] = f2bf(b.w);
    *(uint4*)(xb + i) = pk.v;
    return;
  }
  const int r0 = t >> 4, c4 = (t & 15) * 4;
  if (bid < 3504) {
    const int u = bid - 3072;                  // 432 blocks
    const int mt = u % 12, hw = u / 12;
    const int which = hw / 12, h = hw % 12;
    const float* W = (which == 0) ? WQ : ((which == 1) ? WK : WV);
    const float* src = W + ((size_t)h * 768 + mt * 64) * 64;   // [64 m][64 d]
#pragma unroll
    for (int rep = 0; rep < 4; ++rep) {
      int m = rep * 16 + r0;
      float4 v = *(const float4*)(src + m * 64 + c4);
      T[m][c4] = v.x; T[m][c4 + 1] = v.y; T[m][c4 + 2] = v.z; T[m][c4 + 3] = v.w;
    }
    __syncthreads();
    unsigned short* dst = Wt + ((size_t)which * 768 + h * 64) * 768 + mt * 64;
#pragma unroll
    for (int rep = 0; rep < 4; ++rep) {
      int d = rep * 16 + r0;
      union { unsigned short u[4]; uint2 v; } o;
#pragma unroll
      for (int j = 0; j < 4; ++j) o.u[j] = f2bf(T[c4 + j][d]);
      *(uint2*)(dst + (size_t)d * 768 + c4) = o.v;
    }
  } else {
    const int u = bid - 3504;                  // 144 blocks
    const int m0 = (u % 12) * 64, hd0 = (u / 12) * 64;
#pragma unroll
    for (int rep = 0; rep < 4; ++rep) {
      int i = rep * 16 + r0;                   // hd-local row
      float4 v = *(const float4*)(WO + (size_t)(hd0 + i) * 768 + m0 + c4);
      T[i][c4] = v.x; T[i][c4 + 1] = v.y; T[i][c4 + 2] = v.z; T[i][c4 + 3] = v.w;
    }
    __syncthreads();
#pragma unroll
    for (int rep = 0; rep < 4; ++rep) {
      int m = rep * 16 + r0;                   // m-local row
      union { unsigned short u[4]; uint2 v; } o;
#pragma unroll
      for (int j = 0; j < 4; ++j) o.u[j] = f2bf(T[c4 + j][m]);
      *(uint2*)(Wo_t + (size_t)(m0 + m) * 768 + hd0 + c4) = o.v;
    }
  }
}

// ---------- QKV GEMM: C[M][2304] = A[M][768] * Bt[2304][768]^T ----------
// [round-12 config: 128x128, BK=64, 128B LDS rows + ^(row&7) swizzle,
// A dbuf + B single (48KB, 3 blocks/CU), packed 8B V-transpose stores,
// counted-vmcnt pipeline. 828 TF ~ 92% of the 2-barrier structure ceiling.]
__global__ void __launch_bounds__(256)
gemm_qkv(const unsigned short* __restrict__ A,
         const unsigned short* __restrict__ Bt,
         const float* __restrict__ bq, const float* __restrict__ bk,
         const float* __restrict__ bv,
         unsigned short* __restrict__ qo, unsigned short* __restrict__ ko,
         unsigned short* __restrict__ vo) {
  __shared__ __align__(16) unsigned short ldsA[2 * 8192];   // [buf][128 r][64 k]
  __shared__ __align__(16) unsigned short ldsB[8192];       // [128 r][64 k] single
  const int bm = blockIdx.x, bn = blockIdx.y;
  const int m0 = bm * 128, n0 = bn * 128;
  const int tid = threadIdx.x, w = tid >> 6, lane = tid & 63;
  const int g = lane >> 4, r16 = lane & 15;
  const int wm = w >> 1, wn = w & 1;

  const int ss = (lane & 7) ^ ((lane >> 3) & 7);
  const unsigned short* asrc = A  + (size_t)(m0 + (lane >> 3)) * KD + ss * 8;
  const unsigned short* bsrc = Bt + (size_t)(n0 + (lane >> 3)) * KD + ss * 8;

  auto stageA = [&](int buf, int kt) {     // 4 gloads per wave
#pragma unroll
    for (int j = 0; j < 4; ++j) {
      int seg = w * 4 + j;
      gload16(asrc + (size_t)(seg * 8) * KD + kt * 64, ldsA + buf * 8192 + seg * 512);
    }
  };
  auto stageB = [&](int kt) {              // 4 gloads per wave
#pragma unroll
    for (int j = 0; j < 4; ++j) {
      int seg = w * 4 + j;
      gload16(bsrc + (size_t)(seg * 8) * KD + kt * 64, ldsB + seg * 512);
    }
  };

  const int r7 = r16 & 7;
  const int aoff0 = r16 * 64 + ((g    ) ^ r7) * 8;   // k-chunk g   (kk=0)
  const int aoff1 = r16 * 64 + ((g + 4) ^ r7) * 8;   // k-chunk g+4 (kk=1)

  f32x4 acc[4][4];
  const f32x4 zero4 = {0.f, 0.f, 0.f, 0.f};
#pragma unroll
  for (int i = 0; i < 4; ++i)
#pragma unroll
    for (int j = 0; j < 4; ++j) acc[i][j] = zero4;

  constexpr int NKT = KD / 64;   // 12
  stageA(0, 0);
  stageB(0);
  int buf = 0;
  for (int kt = 0; kt < NKT; ++kt) {
    if (kt + 1 < NKT) {
      stageA(buf ^ 1, kt + 1);
      asm volatile("s_waitcnt vmcnt(4)" ::: "memory");   // A(t)+B(t) landed
    } else {
      asm volatile("s_waitcnt vmcnt(0)" ::: "memory");
    }
    __builtin_amdgcn_s_barrier();                        // everyone's landed
    const unsigned short* Ab = ldsA + buf * 8192 + wm * 4096;
    const unsigned short* Bb = ldsB + wn * 4096;
    bf16x8 af[2][4], bfr[2][4];
#pragma unroll
    for (int f = 0; f < 4; ++f) {
      af[0][f]  = *(const bf16x8*)&Ab[aoff0 + f * 1024];
      af[1][f]  = *(const bf16x8*)&Ab[aoff1 + f * 1024];
      bfr[0][f] = *(const bf16x8*)&Bb[aoff0 + f * 1024];
      bfr[1][f] = *(const bf16x8*)&Bb[aoff1 + f * 1024];
    }
#pragma unroll
    for (int kk = 0; kk < 2; ++kk)
#pragma unroll
      for (int fm = 0; fm < 4; ++fm)
#pragma unroll
        for (int fn = 0; fn < 4; ++fn)
          acc[fm][fn] = __builtin_amdgcn_mfma_f32_16x16x32_bf16(af[kk][fm], bfr[kk][fn],
                                                                acc[fm][fn], 0, 0, 0);
    asm volatile("s_waitcnt lgkmcnt(0)" ::: "memory");   // all ds_reads returned
    __builtin_amdgcn_s_barrier();                        // B buffer now dead
    if (kt + 1 < NKT) stageB(kt + 1);                    // refill B immediately
    buf ^= 1;
  }

#pragma unroll
  for (int fm = 0; fm < 4; ++fm) {
#pragma unroll
    for (int fn = 0; fn < 4; ++fn) {
      const int col = n0 + wn * 64 + fn * 16 + r16;
      const int rbase = m0 + wm * 64 + fm * 16 + g * 4;
      const int which = (col >= 1536) ? 2 : ((col >= 768) ? 1 : 0);
      const int hd = col - which * 768;
      const int h = hd >> 6, d = hd & 63;
      const float bias = (which == 0 ? bq : which == 1 ? bk : bv)[hd];
      if (which == 2) {
        // V transposed: vt[bh][d][s]; 4 r-values are s-consecutive -> 8B store
        union { unsigned short u[4]; uint2 v; } o;
#pragma unroll
        for (int r = 0; r < 4; ++r) o.u[r] = cvt_bf16(acc[fm][fn][r] + bias);
        const int b = rbase >> 11, s = rbase & (SEQL - 1);
        *(uint2*)(vo + ((size_t)(b * NH + h) * DHD + d) * SEQL + s) = o.v;
      } else {
#pragma unroll
        for (int r = 0; r < 4; ++r) {
          int row = rbase + r;
          int b = row >> 11, s = row & (SEQL - 1);
          float v = acc[fm][fn][r] + bias;
          if (which == 0)  // fold 1/sqrt(64)*log2(e) so attn uses exp2 directly
            qo[((size_t)(b * NH + h) * SEQL + s) * DHD + d] = cvt_bf16(v * 0.1803368801111f);
          else
            ko[((size_t)(b * NH + h) * SEQL + s) * DHD + d] = cvt_bf16(v);
        }
      }
    }
  }
}

// ---------- O-proj GEMM: out[M][768] = z[M][768] * Wo_t[768][768]^T + bO ----------
// [round-15 config: 64x128 tile, grid (128,6)=768 blocks=3/CU on all CUs.]
__global__ void __launch_bounds__(256)
gemm_o(const unsigned short* __restrict__ A,
       const unsigned short* __restrict__ Bt,
       const float* __restrict__ bo, float* __restrict__ fout) {
  __shared__ __align__(16) unsigned short ldsA[2 * 4096];   // [buf][64 r][64 k]
  __shared__ __align__(16) unsigned short ldsB[8192];       // [128 r][64 k] single
  const int bm = blockIdx.x, bn = blockIdx.y;
  const int m0 = bm * 64, n0 = bn * 128;
  const int tid = threadIdx.x, w = tid >> 6, lane = tid & 63;
  const int g = lane >> 4, r16 = lane & 15;
  const int wm = w >> 1, wn = w & 1;

  const int ss = (lane & 7) ^ ((lane >> 3) & 7);
  const unsigned short* asrc = A  + (size_t)(m0 + (lane >> 3)) * KD + ss * 8;
  const unsigned short* bsrc = Bt + (size_t)(n0 + (lane >> 3)) * KD + ss * 8;

  auto stageA = [&](int buf, int kt) {     // 2 gloads per wave
#pragma unroll
    for (int j = 0; j < 2; ++j) {
      int seg = w * 2 + j;
      gload16(asrc + (size_t)(seg * 8) * KD + kt * 64, ldsA + buf * 4096 + seg * 512);
    }
  };
  auto stageB = [&](int kt) {              // 4 gloads per wave
#pragma unroll
    for (int j = 0; j < 4; ++j) {
      int seg = w * 4 + j;
      gload16(bsrc + (size_t)(seg * 8) * KD + kt * 64, ldsB + seg * 512);
    }
  };

  const int r7 = r16 & 7;
  const int aoff0 = r16 * 64 + ((g    ) ^ r7) * 8;
  const int aoff1 = r16 * 64 + ((g + 4) ^ r7) * 8;

  f32x4 acc[2][4];
  const f32x4 zero4 = {0.f, 0.f, 0.f, 0.f};
#pragma unroll
  for (int i = 0; i < 2; ++i)
#pragma unroll
    for (int j = 0; j < 4; ++j) acc[i][j] = zero4;

  constexpr int NKT = KD / 64;   // 12
  stageA(0, 0);
  stageB(0);
  int buf = 0;
  for (int kt = 0; kt < NKT; ++kt) {
    if (kt + 1 < NKT) {
      stageA(buf ^ 1, kt + 1);
      asm volatile("s_waitcnt vmcnt(2)" ::: "memory");
    } else {
      asm volatile("s_waitcnt vmcnt(0)" ::: "memory");
    }
    __builtin_amdgcn_s_barrier();
    const unsigned short* Ab = ldsA + buf * 4096 + wm * 2048;   // 32 rows
    const unsigned short* Bb = ldsB + wn * 4096;                // 64 rows
    bf16x8 af[2][2], bfr[2][4];
#pragma unroll
    for (int f = 0; f < 2; ++f) {
      af[0][f] = *(const bf16x8*)&Ab[aoff0 + f * 1024];
      af[1][f] = *(const bf16x8*)&Ab[aoff1 + f * 1024];
    }
#pragma unroll
    for (int f = 0; f < 4; ++f) {
      bfr[0][f] = *(const bf16x8*)&Bb[aoff0 + f * 1024];
      bfr[1][f] = *(const bf16x8*)&Bb[aoff1 + f * 1024];
    }
#pragma unroll
    for (int kk = 0; kk < 2; ++kk)
#pragma unroll
      for (int fm = 0; fm < 2; ++fm)
#pragma unroll
        for (int fn = 0; fn < 4; ++fn)
          acc[fm][fn] = __builtin_amdgcn_mfma_f32_16x16x32_bf16(af[kk][fm], bfr[kk][fn],
                                                                acc[fm][fn], 0, 0, 0);
    asm volatile("s_waitcnt lgkmcnt(0)" ::: "memory");
    __builtin_amdgcn_s_barrier();
    if (kt + 1 < NKT) stageB(kt + 1);
    buf ^= 1;
  }

#pragma unroll
  for (int fm = 0; fm < 2; ++fm) {
#pragma unroll
    for (int fn = 0; fn < 4; ++fn) {
      const int col = n0 + wn * 64 + fn * 16 + r16;
      const int rbase = m0 + wm * 32 + fm * 16 + g * 4;
      const float bias = bo[col];
#pragma unroll
      for (int r = 0; r < 4; ++r)
        fout[(size_t)(rbase + r) * DMOD + col] = acc[fm][fn][r] + bias;
    }
  }
}

// ---------- flash attention (causal, FUSED paired q-tiles, single kv loop) ----------
// Round 20: fuse pass A (q-tile qp) and pass B (q-tile 31-qp) into ONE kv loop
// over kt = 0..qtB. Round-18/19 post-mortem: per-stage serial chain
// QK->softmax->P-roundtrip->PV is ~3500 cyc vs ~620 cyc of MFMA issue
// (MfmaUtil 21%) -- latency-bound; loop rotation (r19) added nothing because
// it added no independent work. Fusion does: kv tiles 0..qtA are needed by
// BOTH q-tiles, so each such stage now carries TWO independent chains
// (saccA/saccB, separate P regions, separate zacc/lacc), interleaved
// QK_B,QK_A -> SM_B,SM_A -> PV_B,PV_A so each phase's latency hides under
// the sibling's issue. Stage count per block drops 33 -> 32-qp (avg 24.5)
// and the overlap region staging traffic halves. LDS 48KB -> 3 blocks/CU.
// vmcnt discipline = round-18 counted style (wait on loads issued one full
// stage earlier = free). grid 768 = 16 qp x 48 bh (48%8==0 -> bh-locality).
__global__ void __launch_bounds__(256, 3)
attn_fwd(const unsigned short* __restrict__ qb,
         const unsigned short* __restrict__ kb,
         const unsigned short* __restrict__ vt,
         unsigned short* __restrict__ zb) {
  __shared__ __align__(16) unsigned short ldsK[2 * 4096];  // [buf][kv 64][d 64] swz
  __shared__ __align__(16) unsigned short ldsV[2 * 4096];  // [buf][d 64][kv 64] swz
  __shared__ __align__(16) unsigned short ldsP[2 * 4096];  // [pass][wave][q 16][kv 64] swz
  const int id = blockIdx.x;
  const int qp = id / 48, bh = id % 48;
  const int qtA = qp, qtB = 31 - qp;
  const int tid = threadIdx.x, w = tid >> 6, lane = tid & 63;
  const int g = lane >> 4, r16 = lane & 15;
  const int r7 = r16 & 7;

  // staging source bases (lane-constant)
  const int sslot = (lane & 7) ^ (lane >> 3);
  const unsigned short* ksrc = kb + (size_t)bh * SEQL * DHD + (lane >> 3) * 64 + sslot * 8;
  const unsigned short* vsrc = vt + (size_t)bh * SEQL * DHD + (lane >> 3) * 2048 + sslot * 8;

  auto stage = [&](int buf, int kv0) {     // 4 gloads per wave
#pragma unroll
    for (int j = 0; j < 2; ++j) {
      int seg = w * 2 + j;
      gload16(ksrc + kv0 * 64 + seg * 512, ldsK + buf * 4096 + seg * 512);
      gload16(vsrc + kv0 + seg * 16384,    ldsV + buf * 4096 + seg * 512);
    }
  };

  // K/V fragment offsets, ushort units (row&7 == r16&7 for all frag rows)
  const int roff0 = r16 * 64 + ((g    ) ^ r7) * 8;   // d/kv chunk kk=0
  const int roff1 = r16 * 64 + ((g + 4) ^ r7) * 8;   // kk=1
  // P buffers: per pass, per wave [16 q][64 kv] bf16, chunk swizzle c ^= r7.
  char* const pwbA = (char*)ldsP + w * 2048;
  char* const pwbB = (char*)ldsP + 8192 + w * 2048;
  int paddr[4];
#pragma unroll
  for (int fn = 0; fn < 4; ++fn)
    paddr[fn] = r16 * 128 + ((((fn * 2) + (g >> 1)) ^ r7) << 4) + ((g & 1) << 3);
  const int prd0 = r16 * 128 + (((g    ) ^ r7) << 4);
  const int prd1 = r16 * 128 + (((g + 4) ^ r7) << 4);
  const int thr = w * 16 + r16 - g * 4;   // causal: mask if fn*16 + r > thr

  // Q fragments for both passes (B-operand: col=q=r16, k=d=g*8..)
  bf16x8 qfA[2], qfB[2];
  {
    const unsigned short* qa = qb + ((size_t)bh * SEQL + qtA * 64 + w * 16 + r16) * DHD + g * 8;
    const unsigned short* qc = qb + ((size_t)bh * SEQL + qtB * 64 + w * 16 + r16) * DHD + g * 8;
    qfA[0] = *(const bf16x8*)qa; qfA[1] = *(const bf16x8*)(qa + 32);
    qfB[0] = *(const bf16x8*)qc; qfB[1] = *(const bf16x8*)(qc + 32);
  }

  float laccA = 0.f, laccB = 0.f;
  f32x4 zaccA[4], zaccB[4], saccA[4], saccB[4];
  const f32x4 zero4 = {0.f, 0.f, 0.f, 0.f};
#pragma unroll
  for (int r = 0; r < 4; ++r) { zaccA[r] = zero4; zaccB[r] = zero4; }

  // QK^T: swapped operands (A = K-frag, B = Q-frag) -> lane holds q = r16,
  // kv rows fn*16 + g*4 + reg.
  auto qk = [&](const bf16x8* qf, f32x4* sacc, int buf) {
    const unsigned short* Kb = ldsK + buf * 4096;
    __builtin_amdgcn_s_setprio(1);
#pragma unroll
    for (int fn = 0; fn < 4; ++fn) {
      bf16x8 kf = *(const bf16x8*)&Kb[roff0 + fn * 1024];
      sacc[fn] = __builtin_amdgcn_mfma_f32_16x16x32_bf16(kf, qf[0], zero4, 0, 0, 0);
    }
#pragma unroll
    for (int fn = 0; fn < 4; ++fn) {
      bf16x8 kf = *(const bf16x8*)&Kb[roff1 + fn * 1024];
      sacc[fn] = __builtin_amdgcn_mfma_f32_16x16x32_bf16(kf, qf[1], sacc[fn], 0, 0, 0);
    }
    __builtin_amdgcn_s_setprio(0);
  };

  // softmax: mask (diag only), exp2, row-sum into lacc, pack + b64 P store
  auto sm = [&](f32x4* sacc, float& lacc, char* pwb, bool diag) {
    if (diag) {                              // kv = fn*16+g*4+r > q = w*16+r16
#pragma unroll
      for (int fn = 0; fn < 4; ++fn)
#pragma unroll
        for (int r = 0; r < 4; ++r)
          if (fn * 16 + r > thr) sacc[fn][r] = -3.0e38f;
    }
#pragma unroll
    for (int fn = 0; fn < 4; ++fn) {
      float p0 = exp2_raw(sacc[fn][0]), p1 = exp2_raw(sacc[fn][1]);
      float p2 = exp2_raw(sacc[fn][2]), p3 = exp2_raw(sacc[fn][3]);
      lacc += (p0 + p1) + (p2 + p3);
      unsigned w0, w1;
      asm("v_cvt_pk_bf16_f32 %0, %1, %2" : "=v"(w0) : "v"(p0), "v"(p1));
      asm("v_cvt_pk_bf16_f32 %0, %1, %2" : "=v"(w1) : "v"(p2), "v"(p3));
      uint2 pk; pk.x = w0; pk.y = w1;
      *(uint2*)(pwb + paddr[fn]) = pk;       // ds_write_b64, addr hoisted
    }
  };

  // PV: A = P-frag (m=q, k=kv), B = V-frag from transposed V tile
  auto pv = [&](char* pwb, f32x4* zacc, int buf) {
    const unsigned short* Vb = ldsV + buf * 4096;
    bf16x8 pf0 = *(const bf16x8*)(pwb + prd0);
    bf16x8 pf1 = *(const bf16x8*)(pwb + prd1);
    __builtin_amdgcn_s_setprio(1);
#pragma unroll
    for (int fn = 0; fn < 4; ++fn) {
      bf16x8 vf = *(const bf16x8*)&Vb[roff0 + fn * 1024];
      zacc[fn] = __builtin_amdgcn_mfma_f32_16x16x32_bf16(pf0, vf, zacc[fn], 0, 0, 0);
    }
#pragma unroll
    for (int fn = 0; fn < 4; ++fn) {
      bf16x8 vf = *(const bf16x8*)&Vb[roff1 + fn * 1024];
      zacc[fn] = __builtin_amdgcn_mfma_f32_16x16x32_bf16(pf1, vf, zacc[fn], 0, 0, 0);
    }
    __builtin_amdgcn_s_setprio(0);
  };

  // ---- prologue: tile 0 fully landed for ALL waves before first compute ----
  stage(0, 0);
  asm volatile("s_waitcnt vmcnt(0)" ::: "memory");
  __builtin_amdgcn_s_barrier();

  int buf = 0;
  for (int kt = 0; kt <= qtB; ++kt) {
    if (kt) __builtin_amdgcn_s_barrier();    // all reads of buf^1 retired
    if (kt < qtB) {
      stage(buf ^ 1, (kt + 1) * 64);
      if (kt) asm volatile("s_waitcnt vmcnt(4)" ::: "memory");  // tile kt landed
    } else {
      asm volatile("s_waitcnt vmcnt(0)" ::: "memory");
    }
    const bool doA = (kt <= qtA);            // block-uniform branch
    qk(qfB, saccB, buf);
    if (doA) qk(qfA, saccA, buf);
    sm(saccB, laccB, pwbB, kt == qtB);
    if (doA) sm(saccA, laccA, pwbA, kt == qtA);
    asm volatile("" ::: "memory");           // order P stores before P reads
    pv(pwbB, zaccB, buf);
    if (doA) pv(pwbA, zaccA, buf);
    buf ^= 1;
  }

  // epilogue: cross-group l-reduce (groups hold disjoint kv), normalize, store
  laccA += __shfl_xor(laccA, 16); laccA += __shfl_xor(laccA, 32);
  laccB += __shfl_xor(laccB, 16); laccB += __shfl_xor(laccB, 32);
  const float invA = 1.0f / laccA;   // valid for q = r16 at every lane
  const float invB = 1.0f / laccB;
  const int b = bh / NH, h = bh % NH;
#pragma unroll
  for (int r = 0; r < 4; ++r) {
    // zacc row q' = g*4+r; its inv lives at lane q' (r16=q', group 0)
    float iar = __shfl(invA, g * 4 + r);
    float ibr = __shfl(invB, g * 4 + r);
    int sA = qtA * 64 + w * 16 + g * 4 + r;
    int sB = qtB * 64 + w * 16 + g * 4 + r;
#pragma unroll
    for (int fn = 0; fn < 4; ++fn) {
      int d = fn * 16 + r16;
      zb[((size_t)(b * SEQL + sA)) * DMOD + h * DHD + d] = cvt_bf16(zaccA[fn][r] * iar);
      zb[((size_t)(b * SEQL + sB)) * DMOD + h * DHD + d] = cvt_bf16(zaccB[fn][r] * ibr);
    }
  }
}

// ---------- launch ----------

extern "C" void kernel_launch(void* const* d_in, const int* in_sizes, int n_in,
                              void* d_out, int out_size, void* d_ws, size_t ws_size,
                              hipStream_t stream) {
  const float* x  = (const float*)d_in[0];
  const float* WQ = (const float*)d_in[1];
  const float* WK = (const float*)d_in[2];
  const float* WV = (const float*)d_in[3];
  const float* WO = (const float*)d_in[4];
  const float* bQ = (const float*)d_in[5];
  const float* bK = (const float*)d_in[6];
  const float* bV = (const float*)d_in[7];
  const float* bO = (const float*)d_in[8];
  float* out = (float*)d_out;

  constexpr size_t NE = (size_t)NT * DMOD;
  unsigned short* w0   = (unsigned short*)d_ws;
  unsigned short* Wqkv = w0;                         // 3*768*768
  unsigned short* Wo   = Wqkv + (size_t)3 * 768 * 768;
  unsigned short* xb   = Wo + (size_t)768 * 768;
  unsigned short* qb   = xb + NE;
  unsigned short* kb   = qb + NE;
  unsigned short* vt   = kb + NE;                    // [bh][d][s]
  unsigned short* zb   = xb;                         // alias: xb dead after QKV GEMM
  size_t need = (size_t)(vt + NE - w0) * sizeof(unsigned short);
  if (ws_size < need) return;

  prep_all<<<3648, 256, 0, stream>>>(x, WQ, WK, WV, WO, xb, Wqkv, Wo);
  gemm_qkv<<<dim3(64, 18), 256, 0, stream>>>(xb, Wqkv, bQ, bK, bV, qb, kb, vt);
  attn_fwd<<<768, 256, 0, stream>>>(qb, kb, vt, zb);
  gemm_o<<<dim3(128, 6), 256, 0, stream>>>(zb, Wo, bO, out);
}